// Round 9
// baseline (461.382 us; speedup 1.0000x reference)
//
#include <hip/hip_runtime.h>
#include <hip/hip_cooperative_groups.h>
#include <math.h>

namespace cg = cooperative_groups;

#define BB 64
#define SS 512
#define DD 256
#define HH 4
#define SCALE 0.0625f  // 1/sqrt(256)
#define PAD 261        // row stride >= 256; odd (261%32=5): row-stride column access is 2-way (free)

__device__ inline float wave_red_sum(float v) {
#pragma unroll
    for (int off = 32; off > 0; off >>= 1) v += __shfl_xor(v, off, 64);
    return v;
}
__device__ inline float wave_red_max(float v) {
#pragma unroll
    for (int off = 32; off > 0; off >>= 1) v = fmaxf(v, __shfl_xor(v, off, 64));
    return v;
}

// One cooperative launch, 512 blocks x 256 threads, 2 blocks/CU (LDS ~71KB).
// A: all blocks stage x tile; blocks 0..15 compute kq/kb.  sync
// B: flash attention per (b, s-tile): dots -> tile softmax -> weighted x-sum.  sync
// C: blocks 0..255 = (b,h): combine tiles, ol = bv + xbar*Wv, wop = ol*Wo.  sync
// D: blocks 0..63 = b: h_pre = sum_h wop + bo + seeds; LayerNorm -> out.
__global__ __launch_bounds__(256) void fused_kernel(
    const float* __restrict__ x, const int* __restrict__ mask,
    const float* __restrict__ seeds,
    const float* __restrict__ Wq, const float* __restrict__ bq,
    const float* __restrict__ Wk, const float* __restrict__ bk,
    const float* __restrict__ Wv, const float* __restrict__ bv,
    const float* __restrict__ Wo, const float* __restrict__ bo,
    const float* __restrict__ gamma, const float* __restrict__ beta,
    float* __restrict__ out,
    float* __restrict__ kqf, float* __restrict__ kbg,
    float* __restrict__ xp, float* __restrict__ mt, float* __restrict__ lt,
    float* __restrict__ wop) {
    cg::grid_group grid = cg::this_grid();
    int blk = blockIdx.x, tid = threadIdx.x, w = tid >> 6, lane = tid & 63;
    int b = blk >> 3, st = blk & 7;

    __shared__ __align__(16) float xt[64][PAD];
    __shared__ __align__(16) float part[4][2][64];  // aliased as sc[4*64] after softmax
    __shared__ __align__(16) float ql[DD];
    __shared__ float red[4][64];
    __shared__ float rb[4];
    float* sc = &part[0][0][0];

    // ---- Phase A1: every block stages its 64x256 x tile into LDS (coalesced float4)
    const float4* xg = reinterpret_cast<const float4*>(x + ((size_t)b * SS + st * 64) * DD);
#pragma unroll
    for (int c = 0; c < 16; ++c) {
        int f = c * 256 + tid;
        float4 v = xg[f];
        int row = f >> 6, col = (f & 63) * 4;
        xt[row][col + 0] = v.x;
        xt[row][col + 1] = v.y;
        xt[row][col + 2] = v.z;
        xt[row][col + 3] = v.w;
    }

    // ---- Phase A2: blocks 0..15 = (h, ds) compute kq[h][ds*64..+64) and kb[h]
    if (blk < 16) {
        int h = blk >> 2, ds = blk & 3;
        // q[h][e], e = tid  (seeds[d] is wave-uniform -> scalar loads)
        float qv = bq[h * DD + tid];
#pragma unroll 8
        for (int d = 0; d < DD; ++d)
            qv = fmaf(seeds[d], Wq[(size_t)d * (HH * DD) + h * DD + tid], qv);
        ql[tid] = qv;
        float t1 = wave_red_sum(bk[h * DD + tid] * qv);
        if (lane == 0) rb[w] = t1;
        __syncthreads();
        if (tid == 0) kbg[h] = rb[0] + rb[1] + rb[2] + rb[3];  // 4 blocks write same value: benign
        // kq partial over e-quarter ec, d = ds*64 + dl
        int dl = tid & 63, ec = tid >> 6;
        int d = ds * 64 + dl;
        const float4* wrow = reinterpret_cast<const float4*>(Wk + (size_t)d * (HH * DD) + h * DD + ec * 64);
        const float4* qq4 = reinterpret_cast<const float4*>(&ql[ec * 64]);
        float acc = 0.f;
#pragma unroll
        for (int e4 = 0; e4 < 16; ++e4) {
            float4 wv = wrow[e4], qq = qq4[e4];
            acc += wv.x * qq.x + wv.y * qq.y + wv.z * qq.z + wv.w * qq.w;
        }
        red[ec][dl] = acc;
        __syncthreads();
        if (tid < 64) kqf[h * DD + ds * 64 + tid] = red[0][tid] + red[1][tid] + red[2][tid] + red[3][tid];
    }
    __threadfence();
    grid.sync();

    // ---- Phase B: flash. wave w: heads {2*(w>>1),+1}, k-half (w&1); lane = s
    {
        int s = lane;
        int hp = w >> 1, kk = w & 1;
        int off = __builtin_amdgcn_readfirstlane(hp * 2 * DD + kk * 128);
        const float* kA = kqf + off;
        const float* kB = kqf + off + DD;
        const float* xrow = &xt[s][kk * 128];
        float a0 = 0.f, a1 = 0.f;
#pragma unroll 16
        for (int k = 0; k < 128; ++k) {
            float xv = xrow[k];
            a0 = fmaf(xv, kA[k], a0);
            a1 = fmaf(xv, kB[k], a1);
        }
        part[w][0][s] = a0;
        part[w][1][s] = a1;
        __syncthreads();

        int h = w;
        float v = part[2 * (h >> 1)][h & 1][s] + part[2 * (h >> 1) + 1][h & 1][s];
        float score = (v + kbg[h]) * SCALE + (1.f - (float)mask[b * SS + st * 64 + s]) * -1e9f;
        float m = wave_red_max(score);
        float p = __expf(score - m);
        float l = wave_red_sum(p);
        __syncthreads();  // all part reads done before aliased write
        sc[h * 64 + s] = p;
        if (lane == 0) {
            mt[blk * 4 + h] = m;
            lt[blk * 4 + h] = l;
        }
        __syncthreads();

        // thread d = tid: o_h[d] = sum_s p[h][s]*xt[s][d]
        float o0 = 0.f, o1 = 0.f, o2 = 0.f, o3 = 0.f;
#pragma unroll 4
        for (int sb = 0; sb < 16; ++sb) {
            float4 p0 = *reinterpret_cast<const float4*>(&sc[0 * 64 + 4 * sb]);
            float4 p1 = *reinterpret_cast<const float4*>(&sc[1 * 64 + 4 * sb]);
            float4 p2 = *reinterpret_cast<const float4*>(&sc[2 * 64 + 4 * sb]);
            float4 p3 = *reinterpret_cast<const float4*>(&sc[3 * 64 + 4 * sb]);
#pragma unroll
            for (int j = 0; j < 4; ++j) {
                float xv = xt[4 * sb + j][tid];
                float pj0 = (j == 0) ? p0.x : (j == 1) ? p0.y : (j == 2) ? p0.z : p0.w;
                float pj1 = (j == 0) ? p1.x : (j == 1) ? p1.y : (j == 2) ? p1.z : p1.w;
                float pj2 = (j == 0) ? p2.x : (j == 1) ? p2.y : (j == 2) ? p2.z : p2.w;
                float pj3 = (j == 0) ? p3.x : (j == 1) ? p3.y : (j == 2) ? p3.z : p3.w;
                o0 = fmaf(pj0, xv, o0);
                o1 = fmaf(pj1, xv, o1);
                o2 = fmaf(pj2, xv, o2);
                o3 = fmaf(pj3, xv, o3);
            }
        }
        float* xpo = xp + (size_t)blk * 4 * DD;
        xpo[0 * DD + tid] = o0;
        xpo[1 * DD + tid] = o1;
        xpo[2 * DD + tid] = o2;
        xpo[3 * DD + tid] = o3;
    }
    __threadfence();
    grid.sync();

    // ---- Phase C: blocks 0..255 = (b2,h2): combine + Wv GEMV + Wo partial GEMV
    if (blk < 256) {
        int b2 = blk >> 2, h2 = blk & 3;
        float* xl = ql;  // reuse LDS
        float* ol = sc;  // reuse LDS
        float M = -3.0e38f;
#pragma unroll
        for (int t = 0; t < 8; ++t) M = fmaxf(M, mt[(b2 * 8 + t) * 4 + h2]);
        float L = 0.f;
        float co[8];
#pragma unroll
        for (int t = 0; t < 8; ++t) {
            co[t] = __expf(mt[(b2 * 8 + t) * 4 + h2] - M);
            L += lt[(b2 * 8 + t) * 4 + h2] * co[t];
        }
        float invL = 1.0f / L;
        float xb = 0.f;
#pragma unroll
        for (int t = 0; t < 8; ++t) xb += co[t] * xp[((size_t)(b2 * 8 + t) * 4 + h2) * DD + tid];
        xl[tid] = xb * invL;
        __syncthreads();
        float acc = bv[h2 * DD + tid];
        const float* wv = Wv + h2 * DD + tid;
#pragma unroll 8
        for (int d = 0; d < DD; ++d) acc = fmaf(xl[d], wv[(size_t)d * (HH * DD)], acc);
        ol[tid] = acc;
        __syncthreads();
        float a2 = 0.f;
        const float* wo = Wo + (size_t)(h2 * DD) * DD + tid;
#pragma unroll 8
        for (int e = 0; e < DD; ++e) a2 = fmaf(ol[e], wo[(size_t)e * DD], a2);
        wop[((size_t)(b2 * HH + h2)) * DD + tid] = a2;
    }
    __threadfence();
    grid.sync();

    // ---- Phase D: blocks 0..63 = b: residual + LayerNorm
    if (blk < 64) {
        float acc = bo[tid] + seeds[tid];
#pragma unroll
        for (int h = 0; h < HH; ++h) acc += wop[((size_t)(blk * HH + h)) * DD + tid];
        float t = wave_red_sum(acc);
        if (lane == 0) rb[w] = t;
        __syncthreads();
        float mu = (rb[0] + rb[1] + rb[2] + rb[3]) * (1.0f / DD);
        float dv = acc - mu;
        float t2 = wave_red_sum(dv * dv);
        __syncthreads();
        if (lane == 0) rb[w] = t2;
        __syncthreads();
        float var = (rb[0] + rb[1] + rb[2] + rb[3]) * (1.0f / DD);
        out[(size_t)blk * DD + tid] = dv * rsqrtf(var + 1e-6f) * gamma[tid] + beta[tid];
    }
}

extern "C" void kernel_launch(void* const* d_in, const int* in_sizes, int n_in,
                              void* d_out, int out_size, void* d_ws, size_t ws_size,
                              hipStream_t stream) {
    const float* x = (const float*)d_in[0];
    const int* mask = (const int*)d_in[1];
    const float* seeds = (const float*)d_in[2];
    const float* Wq = (const float*)d_in[3];
    const float* bq = (const float*)d_in[4];
    const float* Wk = (const float*)d_in[5];
    const float* bk = (const float*)d_in[6];
    const float* Wv = (const float*)d_in[7];
    const float* bv = (const float*)d_in[8];
    const float* Wo = (const float*)d_in[9];
    const float* bo = (const float*)d_in[10];
    const float* gamma = (const float*)d_in[11];
    const float* beta = (const float*)d_in[12];
    float* out = (float*)d_out;

    float* ws = (float*)d_ws;
    float* kqf = ws;              // 1024
    float* kbg = ws + 1024;       // 4 (+12 pad)
    float* mt  = ws + 1040;       // 512*4  = 2048
    float* lt  = ws + 3088;       // 512*4  = 2048
    float* xp  = ws + 5136;       // 512*4*256 = 524288
    float* wop = ws + 529424;     // 64*4*256  = 65536

    void* args[] = {(void*)&x, (void*)&mask, (void*)&seeds,
                    (void*)&Wq, (void*)&bq, (void*)&Wk, (void*)&bk,
                    (void*)&Wv, (void*)&bv, (void*)&Wo, (void*)&bo,
                    (void*)&gamma, (void*)&beta, (void*)&out,
                    (void*)&kqf, (void*)&kbg, (void*)&xp, (void*)&mt, (void*)&lt,
                    (void*)&wop};
    hipLaunchCooperativeKernel((void*)fused_kernel, dim3(BB * 8), dim3(256), args, 0, stream);
}

// Round 11
// 141.458 us; speedup vs baseline: 3.2616x; 3.2616x over previous
//
#include <hip/hip_runtime.h>
#include <math.h>

#define BB 64
#define SS 512
#define DD 256
#define HH 4
#define SCALE 0.0625f  // 1/sqrt(256)

__device__ inline float wave_red_sum(float v) {
#pragma unroll
    for (int off = 32; off > 0; off >>= 1) v += __shfl_xor(v, off, 64);
    return v;
}
__device__ inline float wave_red_max(float v) {
#pragma unroll
    for (int off = 32; off > 0; off >>= 1) v = fmaxf(v, __shfl_xor(v, off, 64));
    return v;
}

// K1: blocks (h, ds): q[h][:] (redundant x4), kb[h], kq[h][ds*64..+64)
__global__ __launch_bounds__(256) void setup_kernel(const float* __restrict__ seeds,
                                                    const float* __restrict__ Wq,
                                                    const float* __restrict__ bq,
                                                    const float* __restrict__ Wk,
                                                    const float* __restrict__ bk,
                                                    float* __restrict__ kqf,
                                                    float* __restrict__ kbg) {
    int blk = blockIdx.x, tid = threadIdx.x, w = tid >> 6, lane = tid & 63;
    int h = blk >> 2, ds = blk & 3;
    __shared__ float ql[DD];
    __shared__ float red[4][64];
    __shared__ float rb[4];
    // q[h][e], e = tid (seeds[d] wave-uniform -> scalar loads)
    float qv = bq[h * DD + tid];
#pragma unroll 8
    for (int d = 0; d < DD; ++d)
        qv = fmaf(seeds[d], Wq[(size_t)d * (HH * DD) + h * DD + tid], qv);
    ql[tid] = qv;
    float t1 = wave_red_sum(bk[h * DD + tid] * qv);
    if (lane == 0) rb[w] = t1;
    __syncthreads();
    if (tid == 0) kbg[h] = rb[0] + rb[1] + rb[2] + rb[3];  // 4 blocks write same value: benign
    // kq partial over e-quarter ec, d = ds*64 + dl
    int dl = tid & 63, ec = tid >> 6;
    int d = ds * 64 + dl;
    const float4* wrow = reinterpret_cast<const float4*>(Wk + (size_t)d * (HH * DD) + h * DD + ec * 64);
    const float4* qq4 = reinterpret_cast<const float4*>(&ql[ec * 64]);
    float acc = 0.f;
#pragma unroll
    for (int e4 = 0; e4 < 16; ++e4) {
        float4 wv = wrow[e4], qq = qq4[e4];
        acc += wv.x * qq.x + wv.y * qq.y + wv.z * qq.z + wv.w * qq.w;
    }
    red[ec][dl] = acc;
    __syncthreads();
    if (tid < 64) kqf[h * DD + ds * 64 + tid] = red[0][tid] + red[1][tid] + red[2][tid] + red[3][tid];
}

// K2: flash. block = (b, st) of 64 rows. x tile in LDS as XOR-swizzled float4:
// xt4[row][chunk ^ (row&7)] — P1 writes free, P2 b128 row reads conflict-free,
// P3 row-contiguous b32 reads free.
__global__ __launch_bounds__(256) void flash_kernel(const float* __restrict__ x,
                                                    const int* __restrict__ mask,
                                                    const float* __restrict__ kqf,
                                                    const float* __restrict__ kbg,
                                                    float* __restrict__ xp,
                                                    float* __restrict__ mt,
                                                    float* __restrict__ lt) {
    int blk = blockIdx.x, tid = threadIdx.x, w = tid >> 6, lane = tid & 63;
    int b = blk >> 3, st = blk & 7;
    __shared__ __align__(16) float4 xt4[64][64];    // 64 KB
    __shared__ __align__(16) float part[4][2][64];  // aliased as sc[256] after softmax
    float* sc = &part[0][0][0];

    // P1: coalesced float4 load, swizzled store
    const float4* xg = reinterpret_cast<const float4*>(x + ((size_t)b * SS + st * 64) * DD);
#pragma unroll
    for (int c = 0; c < 16; ++c) {
        int f = c * 256 + tid;
        int row = f >> 6, ch = f & 63;
        xt4[row][ch ^ (row & 7)] = xg[f];
    }
    __syncthreads();

    // P2: wave w: heads {2*(w>>1), +1}, k-half (w&1); lane = s. b128 reads.
    {
        int s = lane;
        int hp = w >> 1, kk = w & 1;
        int off = __builtin_amdgcn_readfirstlane(hp * 2 * DD + kk * 128);
        const float4* kA4 = reinterpret_cast<const float4*>(kqf + off);
        const float4* kB4 = reinterpret_cast<const float4*>(kqf + off + DD);
        int sx = s & 7;
        float a0 = 0.f, a1 = 0.f;
#pragma unroll
        for (int k4 = 0; k4 < 32; ++k4) {
            float4 xv = xt4[s][(kk * 32 + k4) ^ sx];
            float4 av = kA4[k4], bv = kB4[k4];
            a0 += xv.x * av.x + xv.y * av.y + xv.z * av.z + xv.w * av.w;
            a1 += xv.x * bv.x + xv.y * bv.y + xv.z * bv.z + xv.w * bv.w;
        }
        part[w][0][s] = a0;
        part[w][1][s] = a1;
    }
    __syncthreads();

    // softmax: wave w = head h, lane = s
    {
        int s = lane, h = w;
        float v = part[2 * (h >> 1)][h & 1][s] + part[2 * (h >> 1) + 1][h & 1][s];
        float score = (v + kbg[h]) * SCALE + (1.f - (float)mask[b * SS + st * 64 + s]) * -1e9f;
        float m = wave_red_max(score);
        float p = __expf(score - m);
        float l = wave_red_sum(p);
        __syncthreads();  // all part reads done before aliased write
        sc[h * 64 + s] = p;
        if (lane == 0) {
            mt[blk * 4 + h] = m;
            lt[blk * 4 + h] = l;
        }
    }
    __syncthreads();

    // P3: thread d = tid: o_h[d] = sum_s p[h][s]*xt[s][d]
    {
        float o0 = 0.f, o1 = 0.f, o2 = 0.f, o3 = 0.f;
        int ch = tid >> 2, sub = tid & 3;
#pragma unroll 4
        for (int sb = 0; sb < 16; ++sb) {
            float4 p0 = *reinterpret_cast<const float4*>(&sc[0 * 64 + 4 * sb]);
            float4 p1 = *reinterpret_cast<const float4*>(&sc[1 * 64 + 4 * sb]);
            float4 p2 = *reinterpret_cast<const float4*>(&sc[2 * 64 + 4 * sb]);
            float4 p3 = *reinterpret_cast<const float4*>(&sc[3 * 64 + 4 * sb]);
#pragma unroll
            for (int j = 0; j < 4; ++j) {
                int row = 4 * sb + j;
                float xv = reinterpret_cast<const float*>(&xt4[row][ch ^ (row & 7)])[sub];
                float pj0 = (j == 0) ? p0.x : (j == 1) ? p0.y : (j == 2) ? p0.z : p0.w;
                float pj1 = (j == 0) ? p1.x : (j == 1) ? p1.y : (j == 2) ? p1.z : p1.w;
                float pj2 = (j == 0) ? p2.x : (j == 1) ? p2.y : (j == 2) ? p2.z : p2.w;
                float pj3 = (j == 0) ? p3.x : (j == 1) ? p3.y : (j == 2) ? p3.z : p3.w;
                o0 = fmaf(pj0, xv, o0);
                o1 = fmaf(pj1, xv, o1);
                o2 = fmaf(pj2, xv, o2);
                o3 = fmaf(pj3, xv, o3);
            }
        }
        float* xpo = xp + (size_t)blk * 4 * DD;
        xpo[0 * DD + tid] = o0;
        xpo[1 * DD + tid] = o1;
        xpo[2 * DD + tid] = o2;
        xpo[3 * DD + tid] = o3;
    }
}

// K3: block (b,h): combine tiles -> xbar; ol = bv + xbar*Wv; wop = ol*Wo
__global__ __launch_bounds__(256) void ovwo_kernel(const float* __restrict__ xp,
                                                   const float* __restrict__ mt,
                                                   const float* __restrict__ lt,
                                                   const float* __restrict__ Wv,
                                                   const float* __restrict__ bv,
                                                   const float* __restrict__ Wo,
                                                   float* __restrict__ wop) {
    int b = blockIdx.x >> 2, h = blockIdx.x & 3;
    int tid = threadIdx.x;
    __shared__ float xl[DD];
    __shared__ float ol[DD];
    float M = -3.0e38f;
#pragma unroll
    for (int t = 0; t < 8; ++t) M = fmaxf(M, mt[(b * 8 + t) * 4 + h]);
    float L = 0.f;
    float co[8];
#pragma unroll
    for (int t = 0; t < 8; ++t) {
        co[t] = __expf(mt[(b * 8 + t) * 4 + h] - M);
        L += lt[(b * 8 + t) * 4 + h] * co[t];
    }
    float invL = 1.0f / L;
    float xb = 0.f;
#pragma unroll
    for (int t = 0; t < 8; ++t) xb += co[t] * xp[((size_t)(b * 8 + t) * 4 + h) * DD + tid];
    xl[tid] = xb * invL;
    __syncthreads();
    float acc = bv[h * DD + tid];
    const float* wv = Wv + h * DD + tid;
#pragma unroll 8
    for (int d = 0; d < DD; ++d) acc = fmaf(xl[d], wv[(size_t)d * (HH * DD)], acc);
    ol[tid] = acc;
    __syncthreads();
    float a2 = 0.f;
    const float* wo = Wo + (size_t)(h * DD) * DD + tid;
#pragma unroll 8
    for (int e = 0; e < DD; ++e) a2 = fmaf(ol[e], wo[(size_t)e * DD], a2);
    wop[((size_t)(b * HH + h)) * DD + tid] = a2;
}

// K4: block b: h_pre = sum_h wop + bo + seeds; LayerNorm -> out[b,:]
__global__ __launch_bounds__(256) void ln_kernel(const float* __restrict__ wop,
                                                 const float* __restrict__ bo,
                                                 const float* __restrict__ seeds,
                                                 const float* __restrict__ gamma,
                                                 const float* __restrict__ beta,
                                                 float* __restrict__ out) {
    __shared__ float r1[4], r2[4];
    int b = blockIdx.x, tid = threadIdx.x;
    int w = tid >> 6, lane = tid & 63;
    float acc = bo[tid] + seeds[tid];
#pragma unroll
    for (int h = 0; h < HH; ++h) acc += wop[((size_t)(b * HH + h)) * DD + tid];
    float t = wave_red_sum(acc);
    if (lane == 0) r1[w] = t;
    __syncthreads();
    float mu = (r1[0] + r1[1] + r1[2] + r1[3]) * (1.0f / DD);
    float dv = acc - mu;
    float t2 = wave_red_sum(dv * dv);
    if (lane == 0) r2[w] = t2;
    __syncthreads();
    float var = (r2[0] + r2[1] + r2[2] + r2[3]) * (1.0f / DD);
    out[(size_t)b * DD + tid] = dv * rsqrtf(var + 1e-6f) * gamma[tid] + beta[tid];
}

extern "C" void kernel_launch(void* const* d_in, const int* in_sizes, int n_in,
                              void* d_out, int out_size, void* d_ws, size_t ws_size,
                              hipStream_t stream) {
    const float* x = (const float*)d_in[0];
    const int* mask = (const int*)d_in[1];
    const float* seeds = (const float*)d_in[2];
    const float* Wq = (const float*)d_in[3];
    const float* bq = (const float*)d_in[4];
    const float* Wk = (const float*)d_in[5];
    const float* bk = (const float*)d_in[6];
    const float* Wv = (const float*)d_in[7];
    const float* bv = (const float*)d_in[8];
    const float* Wo = (const float*)d_in[9];
    const float* bo = (const float*)d_in[10];
    const float* gamma = (const float*)d_in[11];
    const float* beta = (const float*)d_in[12];
    float* out = (float*)d_out;

    float* ws = (float*)d_ws;
    float* kqf = ws;              // 1024
    float* kbg = ws + 1024;       // 4 (+12 pad)
    float* mt  = ws + 1040;       // 512*4 = 2048
    float* lt  = ws + 3088;       // 512*4 = 2048
    float* xp  = ws + 5136;       // 512*4*256 = 524288
    float* wop = ws + 529424;     // 64*4*256  = 65536

    setup_kernel<<<16, 256, 0, stream>>>(seeds, Wq, bq, Wk, bk, kqf, kbg);
    flash_kernel<<<BB * 8, 256, 0, stream>>>(x, mask, kqf, kbg, xp, mt, lt);
    ovwo_kernel<<<BB * HH, 256, 0, stream>>>(xp, mt, lt, Wv, bv, Wo, wop);
    ln_kernel<<<BB, 256, 0, stream>>>(wop, bo, seeds, gamma, beta, out);
}